// Round 1
// baseline (889.577 us; speedup 1.0000x reference)
//
#include <hip/hip_runtime.h>

#define NUM_SEG 16

// Piecewise-quadratic 1/sqrt(x):
//   idx = sum_{j=1..15} (x > breaks[j])   (exact searchsorted-1 for x in [LO,HI))
//   out = (a[idx]*x + b[idx])*x + c[idx]
//
// Memory-bound streaming: 1.074 GB HBM traffic/call -> ~170 us floor at the
// 6.3 TB/s achievable ceiling. Input (512 MiB) exceeds the 256 MiB L3, so
// there is ZERO reuse on either stream: load and store nontemporally to skip
// L2/L3 allocation churn. 2x grid-stride unroll keeps two independent 1 KiB
// wave-loads in flight against the ~900-cycle HBM miss latency.
//
// Coeffs live in LDS at float4 stride (one ds_read_b128 gather per element;
// idx distribution is top-heavy -> mostly same-address broadcast, conflict-
// free). Interior breaks are wave-uniform loads -> SGPRs.

typedef float f4 __attribute__((ext_vector_type(4)));

__device__ __forceinline__ f4 eval4(const f4 v, const float* __restrict__ bk,
                                    const f4* __restrict__ lds_coef)
{
    f4 r;
#pragma unroll
    for (int e = 0; e < 4; ++e) {
        const float xv = v[e];
        int idx = 0;
#pragma unroll
        for (int j = 0; j < NUM_SEG - 1; ++j) idx += (xv > bk[j]) ? 1 : 0;
        const f4 cf = lds_coef[idx];
        r[e] = fmaf(fmaf(cf[0], xv, cf[1]), xv, cf[2]);
    }
    return r;
}

__global__ __launch_bounds__(256) void invsqrt_pw_kernel(
    const float* __restrict__ x,
    const float* __restrict__ breaks,
    const float* __restrict__ coeffs,
    float* __restrict__ out,
    int n4, int n)
{
    __shared__ f4 lds_coef[NUM_SEG];

    if (threadIdx.x < NUM_SEG) {
        const int s = threadIdx.x;
        f4 c;
        c[0] = coeffs[3 * s + 0];
        c[1] = coeffs[3 * s + 1];
        c[2] = coeffs[3 * s + 2];
        c[3] = 0.0f;
        lds_coef[s] = c;
    }

    // Interior breaks: wave-uniform loads -> scalar loads -> SGPRs.
    float bk[NUM_SEG - 1];
#pragma unroll
    for (int j = 0; j < NUM_SEG - 1; ++j) bk[j] = breaks[j + 1];

    __syncthreads();

    const f4* __restrict__ x4 = (const f4*)x;
    f4* __restrict__ o4 = (f4*)out;

    const int stride = gridDim.x * blockDim.x;
    int i = blockIdx.x * blockDim.x + threadIdx.x;

    // 2x-unrolled grid-stride: two independent nontemporal streams in flight.
    for (; i + stride < n4; i += 2 * stride) {
        const f4 v0 = __builtin_nontemporal_load(x4 + i);
        const f4 v1 = __builtin_nontemporal_load(x4 + i + stride);
        const f4 r0 = eval4(v0, bk, lds_coef);
        const f4 r1 = eval4(v1, bk, lds_coef);
        __builtin_nontemporal_store(r0, o4 + i);
        __builtin_nontemporal_store(r1, o4 + i + stride);
    }
    if (i < n4) {
        const f4 v0 = __builtin_nontemporal_load(x4 + i);
        const f4 r0 = eval4(v0, bk, lds_coef);
        __builtin_nontemporal_store(r0, o4 + i);
    }

    // Tail (n not divisible by 4) — not hit for the bench shape, kept for safety.
    const int base = n4 << 2;
    const int tail = n - base;
    if (tail > 0 && blockIdx.x == 0 && (int)threadIdx.x < tail) {
        const int k = base + threadIdx.x;
        const float xv = x[k];
        int idx = 0;
#pragma unroll
        for (int j = 0; j < NUM_SEG - 1; ++j) idx += (xv > bk[j]) ? 1 : 0;
        const f4 cf = lds_coef[idx];
        out[k] = fmaf(fmaf(cf[0], xv, cf[1]), xv, cf[2]);
    }
}

extern "C" void kernel_launch(void* const* d_in, const int* in_sizes, int n_in,
                              void* d_out, int out_size, void* d_ws, size_t ws_size,
                              hipStream_t stream)
{
    const float* x      = (const float*)d_in[0];
    const float* breaks = (const float*)d_in[1];
    const float* coeffs = (const float*)d_in[2];
    float* out = (float*)d_out;

    const int n  = in_sizes[0];
    const int n4 = n >> 2;

    const int threads = 256;
    int blocks = 2048;  // 8 wg/CU on 256 CUs -> full 32-wave occupancy
    if ((long long)blocks * threads > (long long)n4 && n4 > 0)
        blocks = (n4 + threads - 1) / threads;
    if (blocks < 1) blocks = 1;

    invsqrt_pw_kernel<<<dim3(blocks), dim3(threads), 0, stream>>>(
        x, breaks, coeffs, out, n4, n);
}

// Round 2
// 864.360 us; speedup vs baseline: 1.0292x; 1.0292x over previous
//
#include <hip/hip_runtime.h>

#define NUM_SEG 16

// Piecewise-quadratic 1/sqrt(x):
//   idx = clip(searchsorted(breaks, x, 'left') - 1, 0, 15)
//       = sum_{j=1..15} (x > breaks[j])          (exact, since breaks[0] <= x < breaks[16])
//   out = (a[idx]*x + b[idx])*x + c[idx]
//
// Memory-bound: 1.074 GB HBM traffic/call -> ~171 us floor at the 6.29 TB/s
// measured copy ceiling. Round-0 measured the kernel slice at ~188 us (91% of
// that ceiling). Round-1 A/B: nontemporal load/store hints + stride-split 2x
// unroll REGRESSED the slice to ~204 us — nt bypasses L2's request coalescing
// with zero reuse-protection upside. Plain cached float4 streaming is optimal.
//
// Coeffs live in LDS padded to float4 stride so the per-lane gather is at
// most 2-way bank-conflicted (free on gfx950). Breaks are wave-uniform ->
// SGPRs.
__global__ __launch_bounds__(256) void invsqrt_pw_kernel(
    const float* __restrict__ x,
    const float* __restrict__ breaks,
    const float* __restrict__ coeffs,
    float* __restrict__ out,
    int n4, int n)
{
    __shared__ float4 lds_coef[NUM_SEG];

    if (threadIdx.x < NUM_SEG) {
        const int s = threadIdx.x;
        lds_coef[s] = make_float4(coeffs[3 * s + 0],
                                  coeffs[3 * s + 1],
                                  coeffs[3 * s + 2], 0.0f);
    }

    // Interior breaks: wave-uniform loads -> SGPRs after hoisting.
    float bk[NUM_SEG - 1];
#pragma unroll
    for (int j = 0; j < NUM_SEG - 1; ++j) bk[j] = breaks[j + 1];

    __syncthreads();

    const float4* __restrict__ x4 = (const float4*)x;
    float4* __restrict__ o4 = (float4*)out;

    const int stride = gridDim.x * blockDim.x;
    for (int i = blockIdx.x * blockDim.x + threadIdx.x; i < n4; i += stride) {
        const float4 v = x4[i];
        float xin[4] = {v.x, v.y, v.z, v.w};
        float r[4];
#pragma unroll
        for (int e = 0; e < 4; ++e) {
            const float xv = xin[e];
            int idx = 0;
#pragma unroll
            for (int j = 0; j < NUM_SEG - 1; ++j) idx += (xv > bk[j]) ? 1 : 0;
            const float4 cf = lds_coef[idx];
            r[e] = fmaf(fmaf(cf.x, xv, cf.y), xv, cf.z);
        }
        o4[i] = make_float4(r[0], r[1], r[2], r[3]);
    }

    // Tail (n not divisible by 4) — not hit for the bench shape, kept for safety.
    const int base = n4 << 2;
    const int tail = n - base;
    if (tail > 0 && blockIdx.x == 0 && (int)threadIdx.x < tail) {
        const int i = base + threadIdx.x;
        const float xv = x[i];
        int idx = 0;
#pragma unroll
        for (int j = 0; j < NUM_SEG - 1; ++j) idx += (xv > bk[j]) ? 1 : 0;
        const float4 cf = lds_coef[idx];
        out[i] = fmaf(fmaf(cf.x, xv, cf.y), xv, cf.z);
    }
}

extern "C" void kernel_launch(void* const* d_in, const int* in_sizes, int n_in,
                              void* d_out, int out_size, void* d_ws, size_t ws_size,
                              hipStream_t stream)
{
    const float* x      = (const float*)d_in[0];
    const float* breaks = (const float*)d_in[1];
    const float* coeffs = (const float*)d_in[2];
    float* out = (float*)d_out;

    const int n  = in_sizes[0];
    const int n4 = n >> 2;

    const int threads = 256;
    int blocks = 2048;  // 8 wg/CU on 256 CUs -> full 32-wave occupancy
    if ((long long)blocks * threads > (long long)n4 && n4 > 0)
        blocks = (n4 + threads - 1) / threads;
    if (blocks < 1) blocks = 1;

    invsqrt_pw_kernel<<<dim3(blocks), dim3(threads), 0, stream>>>(
        x, breaks, coeffs, out, n4, n);
}